// Round 1
// baseline (1509.038 us; speedup 1.0000x reference)
//
#include <hip/hip_runtime.h>

// M=512, N=2048, B=4, L=20, H density 0.02 (row weight ~41, col weight ~10).
#define MM 512
#define NN 2048
#define BB 4
#define LL 20
#define MAXDEG 128      // per-row cap (~13 sigma)
#define EMAX  24576     // edge cap = NT*EPT; actual E ~20973 (+25 sigma headroom)
#define NT    1024
#define EPT   24        // edges per thread (96B -> aligned float4 weight loads)
#define PMAX  8         // max threads spanning one row: floor(127/24)+2 = 7 < 8
#define EPSV  1e-6f

// ---------------- workspace layout (bytes) ----------------
#define WS_ROW_DEG   0          // int[512]
#define WS_ROW_PAD   2048       // int[512*128]
#define WS_ROW_OFFF  264192     // float[512]
#define WS_ROW_PTR   266240     // int[513] (pad to 268416)
#define WS_EDGE_CSR  268416     // uint[EMAX] (row<<16|col), CSR order
#define WS_WDE_P     366720     // float[L*EMAX]  contiguous per layer, 16B-aligned
#define WS_MWDE_P    2332800    // float[L*EMAX]
// total 4,298,880 bytes (~4.1 MB)

// ---- k1: one wave per row, ballot-compact H row into padded list ----
// all 32 chunk loads issued before the serial ballot chain (latency hidden once)
__global__ __launch_bounds__(64)
void build_rows(const float* __restrict__ H, int* __restrict__ row_deg,
                int* __restrict__ row_pad, float* __restrict__ row_offf) {
    int i = blockIdx.x, lane = threadIdx.x;
    const float* hrow = H + (size_t)i * NN;
    float v[32];
    #pragma unroll
    for (int c = 0; c < 32; ++c) v[c] = hrow[c * 64 + lane];
    int base = 0;
    #pragma unroll
    for (int c = 0; c < 32; ++c) {
        bool pred = v[c] != 0.0f;
        unsigned long long mask = __ballot(pred);
        int before = __popcll(mask & ((1ull << lane) - 1ull));
        if (pred) {
            int k = base + before;
            if (k < MAXDEG) row_pad[i * MAXDEG + k] = c * 64 + lane;
        }
        base += __popcll(mask);
    }
    if (lane == 0) {
        row_deg[i] = base < MAXDEG ? base : MAXDEG;
        // off-support entries contribute clip(1.0)=1-eps each to the row product
        row_offf[i] = powf(1.0f - EPSV, (float)(NN - base));
    }
}

// ---- k2: exclusive prefix sum of row degrees (single block) ----
__global__ __launch_bounds__(512)
void scan_rows(const int* __restrict__ row_deg, int* __restrict__ row_ptr) {
    __shared__ int tmp[512];
    int t = threadIdx.x;
    tmp[t] = row_deg[t];
    __syncthreads();
    for (int off = 1; off < 512; off <<= 1) {
        int v = (t >= off) ? tmp[t - off] : 0;
        __syncthreads();
        tmp[t] += v;
        __syncthreads();
    }
    if (t == 0) row_ptr[0] = 0;
    row_ptr[t + 1] = tmp[t];
}

// ---- k3: fill CSR edge list ----
__global__ __launch_bounds__(64)
void fill_csr(const int* __restrict__ row_deg, const int* __restrict__ row_pad,
              const int* __restrict__ row_ptr, unsigned* __restrict__ edge_csr) {
    int i = blockIdx.x, lane = threadIdx.x;
    int deg = row_deg[i], base = row_ptr[i];
    for (int k = lane; k < deg; k += 64)
        edge_csr[base + k] = ((unsigned)i << 16) | (unsigned)row_pad[i * MAXDEG + k];
}

// ---- k4: gather dense weights into CSR-ordered padded layout [l][e] ----
__global__ __launch_bounds__(256)
void gather_weights(const float* __restrict__ w_de, const float* __restrict__ mw_de,
                    const unsigned* __restrict__ edge_csr, const int* __restrict__ row_ptr,
                    float* __restrict__ wde_p, float* __restrict__ mwde_p) {
    int idx = blockIdx.x * 256 + threadIdx.x;   // 0 .. L*EMAX-1
    int l = idx / EMAX, e = idx - l * EMAX;
    int E = row_ptr[MM];
    if (e < E) {
        unsigned pk = edge_csr[e];
        size_t src = (size_t)l * (MM * NN) + (size_t)(pk >> 16) * NN + (pk & 0xffffu);
        wde_p[idx]  = w_de[src];
        mwde_p[idx] = mw_de[src];
    } else {
        wde_p[idx]  = 0.0f;    // padded slots: defined zeros
        mwde_p[idx] = 0.0f;
    }
}

// ---- main BP kernel: ONE workgroup per batch, everything in LDS ----
// No grid barrier, no threadfence, no HBM partial round trips.
__global__ __launch_bounds__(NT)
void nbp_main(const int* __restrict__ synd, const int* __restrict__ errs,
              const float* __restrict__ llrs,
              const float* __restrict__ w_llr, const float* __restrict__ mw_llr,
              const float* __restrict__ rhos, const float* __restrict__ resw,
              const int* __restrict__ row_ptr, const float* __restrict__ row_offf,
              const unsigned* __restrict__ edge_csr,
              const float* __restrict__ wde_p, const float* __restrict__ mwde_p,
              float* __restrict__ out) {
    __shared__ float colsum_s[NN];        // full column sums for current layer
    __shared__ float bel_s[NN];           // belief edge contributions (atomic)
    __shared__ float ncs_s[NN];           // next-layer colsum edge contributions
    __shared__ float partial_s[PMAX * MM];// [q][row] segmented row products
    __shared__ float rowprod_s[MM];
    __shared__ float rp_coef[MM];         // row_offf * (-1)^syndrome
    __shared__ int   rowptr_s[MM + 1];
    __shared__ float rho_n[LL];
    __shared__ float red[16];
    // ~47.2 KB total

    const int b = blockIdx.x;             // one block per batch
    const int tid = threadIdx.x;
    const int lane = tid & 63, wave = tid >> 6;
    const int s0 = EPT * tid;             // this thread's first edge slot

    // ---- prologue ----
    if (tid == 0) {
        float mx = -1e30f;
        for (int l = 0; l < LL; ++l) mx = fmaxf(mx, rhos[l]);
        float s = 0.0f;
        for (int l = 0; l < LL; ++l) { float e = __expf(rhos[l] - mx); rho_n[l] = e; s += e; }
        for (int l = 0; l < LL; ++l) rho_n[l] /= s;
    }
    if (tid < MM) {
        rowptr_s[tid] = row_ptr[tid];
        rp_coef[tid] = row_offf[tid] * (1.0f - 2.0f * (float)synd[b * MM + tid]);
    }
    if (tid == MM) rowptr_s[MM] = row_ptr[MM];

    // each thread permanently owns output columns j0, j1
    const int j0 = tid, j1 = tid + NT;
    const float llr0 = llrs[j0], llr1 = llrs[j1];
    const float ef0 = 1.0f - (float)errs[b * NN + j0];
    const float ef1 = 1.0f - (float)errs[b * NN + j1];
    colsum_s[j0] = llr0 * w_llr[j0];      // layer-0 colsum: msgs are zero
    colsum_s[j1] = llr1 * w_llr[j1];
    bel_s[j0] = 0.0f; bel_s[j1] = 0.0f;
    ncs_s[j0] = 0.0f; ncs_s[j1] = 0.0f;

    int cnt = row_ptr[MM];
    if (cnt > EMAX) cnt = EMAX;

    // per-thread contiguous edge state (CSR order)
    unsigned idx[EPT];
    float msg[EPT], d_r[EPT];
    #pragma unroll
    for (int k = 0; k < EPT; ++k) {
        int e = s0 + k;
        idx[k] = edge_csr[e < cnt ? e : (cnt - 1)];   // padded: clone last real edge
        msg[k] = 0.0f;
    }
    __syncthreads();

    float loss = 0.0f;

    for (int l = 0; l < LL; ++l) {
        const float rw = resw[l];
        const bool last = (l + 1 == LL);

        // ---- issue coalesced weight loads early (consumed in phase D/E) ----
        float mv[EPT], wn[EPT];
        {
            const float4* mp = (const float4*)(mwde_p + (size_t)l * EMAX + s0);
            #pragma unroll
            for (int q = 0; q < EPT / 4; ++q) {
                float4 t4 = mp[q];
                mv[4*q] = t4.x; mv[4*q+1] = t4.y; mv[4*q+2] = t4.z; mv[4*q+3] = t4.w;
            }
            if (!last) {
                const float4* wp = (const float4*)(wde_p + (size_t)(l + 1) * EMAX + s0);
                #pragma unroll
                for (int q = 0; q < EPT / 4; ++q) {
                    float4 t4 = wp[q];
                    wn[4*q] = t4.x; wn[4*q+1] = t4.y; wn[4*q+2] = t4.z; wn[4*q+3] = t4.w;
                }
            } else {
                #pragma unroll
                for (int k = 0; k < EPT; ++k) wn[k] = 0.0f;
            }
        }
        float mwl0 = mw_llr[l * NN + j0], mwl1 = mw_llr[l * NN + j1];
        float wl0 = 0.0f, wl1 = 0.0f;
        if (!last) { wl0 = w_llr[(l + 1) * NN + j0]; wl1 = w_llr[(l + 1) * NN + j1]; }

        // ---- B: per-edge tanh (d), kept in registers ----
        #pragma unroll
        for (int k = 0; k < EPT; ++k) {
            int j = idx[k] & 0xffffu;
            float en = colsum_s[j] - msg[k];
            float t = __expf(en);                             // tanh(en/2)=1-2/(e^en+1)
            float d = 1.0f - 2.0f * __builtin_amdgcn_rcpf(t + 1.0f);
            if (d == 0.0f) d = 1.0f;                          // ref: where(d==0,1,d)
            d = fminf(fmaxf(d, -1.0f + EPSV), 1.0f - EPSV);
            d_r[k] = d;
        }
        // segmented per-row partial products (registers -> <=3 LDS writes)
        if (s0 < cnt) {
            int crow = idx[0] >> 16;
            int q = tid - rowptr_s[crow] / EPT;   // slot within row's thread span
            float p = 1.0f;
            #pragma unroll
            for (int k = 0; k < EPT; ++k) {
                int rk = idx[k] >> 16;
                if (rk != crow) {                 // row starts inside this thread -> q=0
                    partial_s[q * MM + crow] = p;
                    crow = rk; q = 0; p = 1.0f;
                }
                if (s0 + k < cnt) p *= d_r[k];    // padded slots contribute 1.0
            }
            partial_s[q * MM + crow] = p;
        }
        __syncthreads();

        // ---- C: combine <=7 partials per row (lane-consecutive, conflict-free) ----
        if (tid < MM) {
            int lo = rowptr_s[tid], hi = rowptr_s[tid + 1];
            float p = 1.0f;
            if (hi > lo) {
                int f = lo / EPT;
                int span = (hi - 1) / EPT - f + 1;
                for (int q = 0; q < span; ++q) p *= partial_s[q * MM + tid];
            }
            rowprod_s[tid] = p * rp_coef[tid];    // sign + off-support factor folded in
        }
        __syncthreads();

        // ---- D: atanh + msg update + dual LDS scatter (bel + next colsum) ----
        #pragma unroll
        for (int k = 0; k < EPT; ++k) {
            int il = idx[k] >> 16;
            int j  = idx[k] & 0xffffu;
            float rq = rowprod_s[il] * __builtin_amdgcn_rcpf(d_r[k]);
            // sgn*2*atanh(x) = 2*atanh(sgn*x); sgn folded into rp_coef
            float v = __logf(1.0f + rq) - __logf(1.0f - rq) + rw * msg[k];
            msg[k] = v;
            if (s0 + k < cnt) {
                atomicAdd(&bel_s[j], v * mv[k]);
                if (!last) atomicAdd(&ncs_s[j], v * wn[k]);
            }
        }
        __syncthreads();

        // ---- E: loss on own 2 columns + next-layer colsum + re-zero partials ----
        {
            float bel0 = llr0 * mwl0 + bel_s[j0];
            float bel1 = llr1 * mwl1 + bel_s[j1];
            bel_s[j0] = 0.0f; bel_s[j1] = 0.0f;
            float sp0 = fmaxf(bel0, 0.0f) + log1pf(__expf(-fabsf(bel0)));  // softplus
            float sp1 = fmaxf(bel1, 0.0f) + log1pf(__expf(-fabsf(bel1)));
            loss += rho_n[l] * ((sp0 - ef0 * bel0) + (sp1 - ef1 * bel1));
            if (!last) {
                colsum_s[j0] = llr0 * wl0 + ncs_s[j0];
                colsum_s[j1] = llr1 * wl1 + ncs_s[j1];
                ncs_s[j0] = 0.0f; ncs_s[j1] = 0.0f;
            }
        }
        __syncthreads();
    }

    // ---- block reduction of loss, then one global atomic ----
    #pragma unroll
    for (int off = 32; off > 0; off >>= 1) loss += __shfl_down(loss, off);
    if (lane == 0) red[wave] = loss;
    __syncthreads();
    if (wave == 0) {
        float v = (lane < 16) ? red[lane] : 0.0f;
        #pragma unroll
        for (int off = 8; off > 0; off >>= 1) v += __shfl_down(v, off);
        if (lane == 0) atomicAdd(out, v * 0.25f);
    }
}

extern "C" void kernel_launch(void* const* d_in, const int* in_sizes, int n_in,
                              void* d_out, int out_size, void* d_ws, size_t ws_size,
                              hipStream_t stream) {
    const int*   synd  = (const int*)  d_in[0];
    const int*   errs  = (const int*)  d_in[1];
    const float* H     = (const float*)d_in[2];
    const float* llrs  = (const float*)d_in[3];
    const float* w_de  = (const float*)d_in[4];
    const float* w_llr = (const float*)d_in[5];
    const float* mw_de = (const float*)d_in[6];
    const float* mw_llr= (const float*)d_in[7];
    const float* rhos  = (const float*)d_in[8];
    const float* resw  = (const float*)d_in[9];

    char* ws = (char*)d_ws;
    int*      row_deg  = (int*)     (ws + WS_ROW_DEG);
    int*      row_pad  = (int*)     (ws + WS_ROW_PAD);
    float*    row_offf = (float*)   (ws + WS_ROW_OFFF);
    int*      row_ptr  = (int*)     (ws + WS_ROW_PTR);
    unsigned* edge_csr = (unsigned*)(ws + WS_EDGE_CSR);
    float*    wde_p    = (float*)   (ws + WS_WDE_P);
    float*    mwde_p   = (float*)   (ws + WS_MWDE_P);
    float*    out      = (float*)d_out;

    hipMemsetAsync(d_out, 0, sizeof(float), stream);

    build_rows<<<MM, 64, 0, stream>>>(H, row_deg, row_pad, row_offf);
    scan_rows<<<1, 512, 0, stream>>>(row_deg, row_ptr);
    fill_csr<<<MM, 64, 0, stream>>>(row_deg, row_pad, row_ptr, edge_csr);
    gather_weights<<<(LL * EMAX) / 256, 256, 0, stream>>>(w_de, mw_de, edge_csr,
                                                          row_ptr, wde_p, mwde_p);
    nbp_main<<<BB, NT, 0, stream>>>(synd, errs, llrs, w_llr, mw_llr, rhos, resw,
                                    row_ptr, row_offf, edge_csr, wde_p, mwde_p, out);
}

// Round 2
// 1450.565 us; speedup vs baseline: 1.0403x; 1.0403x over previous
//
#include <hip/hip_runtime.h>

// M=512, N=2048, B=4, L=20, H density 0.02 (row weight ~41, col weight ~10).
#define MM 512
#define NN 2048
#define BB 4
#define LL 20
#define MAXDEG 128      // per-row cap (~13 sigma)
#define EMAX  24576     // edge cap = NT*EPT; actual E ~20973 (+25 sigma headroom)
#define NT    1024
#define EPT   24        // edges per thread (96B -> aligned float4 weight loads)
#define PMAX  8         // max threads spanning one row: floor(127/24)+2 = 7 < 8
#define EPSV  1e-6f

// ---------------- workspace layout (bytes) ----------------
#define WS_ROW_DEG   0          // int[512]
#define WS_ROW_PAD   2048       // int[512*128]
#define WS_ROW_OFFF  264192     // float[512]
#define WS_ROW_PTR   266240     // int[513] (pad to 268416)
#define WS_EDGE_CSR  268416     // uint[EMAX] (row<<16|col), CSR order
#define WS_WDE_P     366720     // float[L*EMAX]  contiguous per layer, 16B-aligned
#define WS_MWDE_P    2332800    // float[L*EMAX]
// total 4,298,880 bytes (~4.1 MB)

// ---- k1: one wave per row, ballot-compact H row into padded list ----
__global__ __launch_bounds__(64)
void build_rows(const float* __restrict__ H, int* __restrict__ row_deg,
                int* __restrict__ row_pad, float* __restrict__ row_offf) {
    int i = blockIdx.x, lane = threadIdx.x;
    const float* hrow = H + (size_t)i * NN;
    float v[32];
    #pragma unroll
    for (int c = 0; c < 32; ++c) v[c] = hrow[c * 64 + lane];
    int base = 0;
    #pragma unroll
    for (int c = 0; c < 32; ++c) {
        bool pred = v[c] != 0.0f;
        unsigned long long mask = __ballot(pred);
        int before = __popcll(mask & ((1ull << lane) - 1ull));
        if (pred) {
            int k = base + before;
            if (k < MAXDEG) row_pad[i * MAXDEG + k] = c * 64 + lane;
        }
        base += __popcll(mask);
    }
    if (lane == 0) {
        row_deg[i] = base < MAXDEG ? base : MAXDEG;
        // off-support entries contribute clip(1.0)=1-eps each to the row product
        row_offf[i] = powf(1.0f - EPSV, (float)(NN - base));
    }
}

// ---- k2: exclusive prefix sum of row degrees (single block) ----
__global__ __launch_bounds__(512)
void scan_rows(const int* __restrict__ row_deg, int* __restrict__ row_ptr) {
    __shared__ int tmp[512];
    int t = threadIdx.x;
    tmp[t] = row_deg[t];
    __syncthreads();
    for (int off = 1; off < 512; off <<= 1) {
        int v = (t >= off) ? tmp[t - off] : 0;
        __syncthreads();
        tmp[t] += v;
        __syncthreads();
    }
    if (t == 0) row_ptr[0] = 0;
    row_ptr[t + 1] = tmp[t];
}

// ---- k3: fill CSR edge list ----
__global__ __launch_bounds__(64)
void fill_csr(const int* __restrict__ row_deg, const int* __restrict__ row_pad,
              const int* __restrict__ row_ptr, unsigned* __restrict__ edge_csr) {
    int i = blockIdx.x, lane = threadIdx.x;
    int deg = row_deg[i], base = row_ptr[i];
    for (int k = lane; k < deg; k += 64)
        edge_csr[base + k] = ((unsigned)i << 16) | (unsigned)row_pad[i * MAXDEG + k];
}

// ---- k4: gather dense weights into CSR-ordered padded layout [l][e] ----
__global__ __launch_bounds__(256)
void gather_weights(const float* __restrict__ w_de, const float* __restrict__ mw_de,
                    const unsigned* __restrict__ edge_csr, const int* __restrict__ row_ptr,
                    float* __restrict__ wde_p, float* __restrict__ mwde_p) {
    int idx = blockIdx.x * 256 + threadIdx.x;   // 0 .. L*EMAX-1
    int l = idx / EMAX, e = idx - l * EMAX;
    int E = row_ptr[MM];
    if (e < E) {
        unsigned pk = edge_csr[e];
        size_t src = (size_t)l * (MM * NN) + (size_t)(pk >> 16) * NN + (pk & 0xffffu);
        wde_p[idx]  = w_de[src];
        mwde_p[idx] = mw_de[src];
    } else {
        wde_p[idx]  = 0.0f;    // padded slots: defined zeros
        mwde_p[idx] = 0.0f;
    }
}

// ---- main BP kernel: ONE workgroup per batch, everything in LDS ----
// No grid barrier, no threadfence, no HBM partial round trips.
// __launch_bounds__(1024, 4): exactly 4 waves/EU -> 128-VGPR budget (the
// unqualified form made the compiler cap at 64 VGPRs and spill ~150 live
// floats to scratch -> 5.4x regression in round 1).
__global__ __launch_bounds__(NT, 4)
void nbp_main(const int* __restrict__ synd, const int* __restrict__ errs,
              const float* __restrict__ llrs,
              const float* __restrict__ w_llr, const float* __restrict__ mw_llr,
              const float* __restrict__ rhos, const float* __restrict__ resw,
              const int* __restrict__ row_ptr, const float* __restrict__ row_offf,
              const unsigned* __restrict__ edge_csr,
              const float* __restrict__ wde_p, const float* __restrict__ mwde_p,
              float* __restrict__ out) {
    __shared__ float colsum_s[NN];        // full column sums for current layer
    __shared__ float bel_s[NN];           // belief edge contributions (atomic)
    __shared__ float ncs_s[NN];           // next-layer colsum edge contributions
    __shared__ float partial_s[PMAX * MM];// [q][row] segmented row products
    __shared__ float rowprod_s[MM];
    __shared__ float rp_coef[MM];         // row_offf * (-1)^syndrome
    __shared__ int   rowptr_s[MM + 1];
    __shared__ float rho_n[LL];
    __shared__ float red[16];
    // ~47.2 KB total

    const int b = blockIdx.x;             // one block per batch
    const int tid = threadIdx.x;
    const int lane = tid & 63, wave = tid >> 6;
    const int s0 = EPT * tid;             // this thread's first edge slot

    // ---- prologue ----
    if (tid == 0) {
        float mx = -1e30f;
        for (int l = 0; l < LL; ++l) mx = fmaxf(mx, rhos[l]);
        float s = 0.0f;
        for (int l = 0; l < LL; ++l) { float e = __expf(rhos[l] - mx); rho_n[l] = e; s += e; }
        for (int l = 0; l < LL; ++l) rho_n[l] /= s;
    }
    if (tid < MM) {
        rowptr_s[tid] = row_ptr[tid];
        rp_coef[tid] = row_offf[tid] * (1.0f - 2.0f * (float)synd[b * MM + tid]);
    }
    if (tid == MM) rowptr_s[MM] = row_ptr[MM];

    // each thread permanently owns output columns j0, j1
    const int j0 = tid, j1 = tid + NT;
    const float llr0 = llrs[j0], llr1 = llrs[j1];
    const float ef0 = 1.0f - (float)errs[b * NN + j0];
    const float ef1 = 1.0f - (float)errs[b * NN + j1];
    colsum_s[j0] = llr0 * w_llr[j0];      // layer-0 colsum: msgs are zero
    colsum_s[j1] = llr1 * w_llr[j1];
    bel_s[j0] = 0.0f; bel_s[j1] = 0.0f;
    ncs_s[j0] = 0.0f; ncs_s[j1] = 0.0f;

    int cnt = row_ptr[MM];
    if (cnt > EMAX) cnt = EMAX;

    // per-thread contiguous edge state (CSR order): 72 persistent VGPRs total
    unsigned idx[EPT];
    float msg[EPT], d_r[EPT];
    #pragma unroll
    for (int k = 0; k < EPT; ++k) {
        int e = s0 + k;
        idx[k] = edge_csr[e < cnt ? e : (cnt - 1)];   // padded: clone last real edge
        msg[k] = 0.0f;
    }
    __syncthreads();

    float loss = 0.0f;

    for (int l = 0; l < LL; ++l) {
        const float rw = resw[l];
        const bool last = (l + 1 == LL);

        // ---- B: per-edge tanh (d), kept in registers ----
        #pragma unroll
        for (int k = 0; k < EPT; ++k) {
            int j = idx[k] & 0xffffu;
            float en = colsum_s[j] - msg[k];
            float t = __expf(en);                             // tanh(en/2)=1-2/(e^en+1)
            float d = 1.0f - 2.0f * __builtin_amdgcn_rcpf(t + 1.0f);
            if (d == 0.0f) d = 1.0f;                          // ref: where(d==0,1,d)
            d = fminf(fmaxf(d, -1.0f + EPSV), 1.0f - EPSV);
            d_r[k] = d;
        }
        // segmented per-row partial products (registers -> <=3 LDS writes)
        if (s0 < cnt) {
            int crow = idx[0] >> 16;
            int q = tid - rowptr_s[crow] / EPT;   // slot within row's thread span
            float p = 1.0f;
            #pragma unroll
            for (int k = 0; k < EPT; ++k) {
                int rk = idx[k] >> 16;
                if (rk != crow) {                 // row starts inside this thread -> q=0
                    partial_s[q * MM + crow] = p;
                    crow = rk; q = 0; p = 1.0f;
                }
                if (s0 + k < cnt) p *= d_r[k];    // padded slots contribute 1.0
            }
            partial_s[q * MM + crow] = p;
        }
        __syncthreads();

        // ---- C: combine <=7 partials per row (lane-consecutive, conflict-free) ----
        if (tid < MM) {
            int lo = rowptr_s[tid], hi = rowptr_s[tid + 1];
            float p = 1.0f;
            if (hi > lo) {
                int f = lo / EPT;
                int span = (hi - 1) / EPT - f + 1;
                for (int q = 0; q < span; ++q) p *= partial_s[q * MM + tid];
            }
            rowprod_s[tid] = p * rp_coef[tid];    // sign + off-support factor folded in
        }
        __syncthreads();

        // ---- D: atanh + msg update + dual LDS scatter (bel + next colsum) ----
        // Weights streamed in 6 float4 chunks, 1-ahead double buffer; chunk
        // boundaries pinned with sched_barrier so the unroller can't hoist all
        // 12 loads and blow the register budget.
        {
            const float4* mp = (const float4*)(mwde_p + (size_t)l * EMAX + s0);
            const float4* wp = (const float4*)(wde_p + (size_t)(l + 1) * EMAX + s0);
            float4 mq0 = mp[0];
            float4 wq0 = last ? make_float4(0.f, 0.f, 0.f, 0.f) : wp[0];
            #pragma unroll
            for (int q = 0; q < EPT / 4; ++q) {
                float4 mq1 = make_float4(0.f, 0.f, 0.f, 0.f);
                float4 wq1 = make_float4(0.f, 0.f, 0.f, 0.f);
                if (q + 1 < EPT / 4) {
                    mq1 = mp[q + 1];
                    if (!last) wq1 = wp[q + 1];
                }
                const float mvv[4] = {mq0.x, mq0.y, mq0.z, mq0.w};
                const float wnv[4] = {wq0.x, wq0.y, wq0.z, wq0.w};
                #pragma unroll
                for (int kk = 0; kk < 4; ++kk) {
                    const int k = 4 * q + kk;
                    int il = idx[k] >> 16;
                    int j  = idx[k] & 0xffffu;
                    float rq = rowprod_s[il] * __builtin_amdgcn_rcpf(d_r[k]);
                    // sgn*2*atanh(x) = 2*atanh(sgn*x); sgn folded into rp_coef
                    float v = __logf(1.0f + rq) - __logf(1.0f - rq) + rw * msg[k];
                    msg[k] = v;
                    if (s0 + k < cnt) {
                        atomicAdd(&bel_s[j], v * mvv[kk]);
                        if (!last) atomicAdd(&ncs_s[j], v * wnv[kk]);
                    }
                }
                mq0 = mq1; wq0 = wq1;
                __builtin_amdgcn_sched_barrier(0);
            }
        }
        __syncthreads();

        // ---- E: loss on own 2 columns + next-layer colsum + re-zero partials ----
        {
            float bel0 = llr0 * mw_llr[l * NN + j0] + bel_s[j0];
            float bel1 = llr1 * mw_llr[l * NN + j1] + bel_s[j1];
            bel_s[j0] = 0.0f; bel_s[j1] = 0.0f;
            float sp0 = fmaxf(bel0, 0.0f) + log1pf(__expf(-fabsf(bel0)));  // softplus
            float sp1 = fmaxf(bel1, 0.0f) + log1pf(__expf(-fabsf(bel1)));
            loss += rho_n[l] * ((sp0 - ef0 * bel0) + (sp1 - ef1 * bel1));
            if (!last) {
                colsum_s[j0] = llr0 * w_llr[(l + 1) * NN + j0] + ncs_s[j0];
                colsum_s[j1] = llr1 * w_llr[(l + 1) * NN + j1] + ncs_s[j1];
                ncs_s[j0] = 0.0f; ncs_s[j1] = 0.0f;
            }
        }
        __syncthreads();
    }

    // ---- block reduction of loss, then one global atomic ----
    #pragma unroll
    for (int off = 32; off > 0; off >>= 1) loss += __shfl_down(loss, off);
    if (lane == 0) red[wave] = loss;
    __syncthreads();
    if (wave == 0) {
        float v = (lane < 16) ? red[lane] : 0.0f;
        #pragma unroll
        for (int off = 8; off > 0; off >>= 1) v += __shfl_down(v, off);
        if (lane == 0) atomicAdd(out, v * 0.25f);
    }
}

extern "C" void kernel_launch(void* const* d_in, const int* in_sizes, int n_in,
                              void* d_out, int out_size, void* d_ws, size_t ws_size,
                              hipStream_t stream) {
    const int*   synd  = (const int*)  d_in[0];
    const int*   errs  = (const int*)  d_in[1];
    const float* H     = (const float*)d_in[2];
    const float* llrs  = (const float*)d_in[3];
    const float* w_de  = (const float*)d_in[4];
    const float* w_llr = (const float*)d_in[5];
    const float* mw_de = (const float*)d_in[6];
    const float* mw_llr= (const float*)d_in[7];
    const float* rhos  = (const float*)d_in[8];
    const float* resw  = (const float*)d_in[9];

    char* ws = (char*)d_ws;
    int*      row_deg  = (int*)     (ws + WS_ROW_DEG);
    int*      row_pad  = (int*)     (ws + WS_ROW_PAD);
    float*    row_offf = (float*)   (ws + WS_ROW_OFFF);
    int*      row_ptr  = (int*)     (ws + WS_ROW_PTR);
    unsigned* edge_csr = (unsigned*)(ws + WS_EDGE_CSR);
    float*    wde_p    = (float*)   (ws + WS_WDE_P);
    float*    mwde_p   = (float*)   (ws + WS_MWDE_P);
    float*    out      = (float*)d_out;

    hipMemsetAsync(d_out, 0, sizeof(float), stream);

    build_rows<<<MM, 64, 0, stream>>>(H, row_deg, row_pad, row_offf);
    scan_rows<<<1, 512, 0, stream>>>(row_deg, row_ptr);
    fill_csr<<<MM, 64, 0, stream>>>(row_deg, row_pad, row_ptr, edge_csr);
    gather_weights<<<(LL * EMAX) / 256, 256, 0, stream>>>(w_de, mw_de, edge_csr,
                                                          row_ptr, wde_p, mwde_p);
    nbp_main<<<BB, NT, 0, stream>>>(synd, errs, llrs, w_llr, mw_llr, rhos, resw,
                                    row_ptr, row_offf, edge_csr, wde_p, mwde_p, out);
}

// Round 3
// 1444.872 us; speedup vs baseline: 1.0444x; 1.0039x over previous
//
#include <hip/hip_runtime.h>

// M=512, N=2048, B=4, L=20, H density 0.02 (row weight ~41, col weight ~10).
#define MM 512
#define NN 2048
#define BB 4
#define LL 20
#define MAXDEG 128      // per-row cap (~13 sigma)
#define EMAX  24576     // edge cap = NT*EPT; actual E ~20973 (+25 sigma headroom)
#define NT    1024
#define EPT   24        // edges per thread (96B -> aligned float4 weight loads)
#define PMAX  8         // max threads spanning one row: floor(127/24)+2 = 7 < 8
#define EPSV  1e-6f

// ---------------- workspace layout (bytes) ----------------
#define WS_ROW_DEG   0          // int[512]
#define WS_ROW_PAD   2048       // int[512*128]
#define WS_ROW_OFFF  264192     // float[512]
#define WS_ROW_PTR   266240     // int[513] (pad to 268416)
#define WS_EDGE_CSR  268416     // uint[EMAX] (row<<16|col), CSR order
#define WS_WDE_P     366720     // float[L*EMAX]  contiguous per layer, 16B-aligned
#define WS_MWDE_P    2332800    // float[L*EMAX]
// total 4,298,880 bytes (~4.1 MB)

// ---- k1: one wave per row, ballot-compact H row into padded list ----
__global__ __launch_bounds__(64)
void build_rows(const float* __restrict__ H, int* __restrict__ row_deg,
                int* __restrict__ row_pad, float* __restrict__ row_offf) {
    int i = blockIdx.x, lane = threadIdx.x;
    const float* hrow = H + (size_t)i * NN;
    float v[32];
    #pragma unroll
    for (int c = 0; c < 32; ++c) v[c] = hrow[c * 64 + lane];
    int base = 0;
    #pragma unroll
    for (int c = 0; c < 32; ++c) {
        bool pred = v[c] != 0.0f;
        unsigned long long mask = __ballot(pred);
        int before = __popcll(mask & ((1ull << lane) - 1ull));
        if (pred) {
            int k = base + before;
            if (k < MAXDEG) row_pad[i * MAXDEG + k] = c * 64 + lane;
        }
        base += __popcll(mask);
    }
    if (lane == 0) {
        row_deg[i] = base < MAXDEG ? base : MAXDEG;
        // off-support entries contribute clip(1.0)=1-eps each to the row product
        row_offf[i] = powf(1.0f - EPSV, (float)(NN - base));
    }
}

// ---- k2: exclusive prefix sum of row degrees (single block) ----
__global__ __launch_bounds__(512)
void scan_rows(const int* __restrict__ row_deg, int* __restrict__ row_ptr) {
    __shared__ int tmp[512];
    int t = threadIdx.x;
    tmp[t] = row_deg[t];
    __syncthreads();
    for (int off = 1; off < 512; off <<= 1) {
        int v = (t >= off) ? tmp[t - off] : 0;
        __syncthreads();
        tmp[t] += v;
        __syncthreads();
    }
    if (t == 0) row_ptr[0] = 0;
    row_ptr[t + 1] = tmp[t];
}

// ---- k3: fill CSR edge list ----
__global__ __launch_bounds__(64)
void fill_csr(const int* __restrict__ row_deg, const int* __restrict__ row_pad,
              const int* __restrict__ row_ptr, unsigned* __restrict__ edge_csr) {
    int i = blockIdx.x, lane = threadIdx.x;
    int deg = row_deg[i], base = row_ptr[i];
    for (int k = lane; k < deg; k += 64)
        edge_csr[base + k] = ((unsigned)i << 16) | (unsigned)row_pad[i * MAXDEG + k];
}

// ---- k4: gather dense weights into CSR-ordered padded layout [l][e] ----
__global__ __launch_bounds__(256)
void gather_weights(const float* __restrict__ w_de, const float* __restrict__ mw_de,
                    const unsigned* __restrict__ edge_csr, const int* __restrict__ row_ptr,
                    float* __restrict__ wde_p, float* __restrict__ mwde_p) {
    int idx = blockIdx.x * 256 + threadIdx.x;   // 0 .. L*EMAX-1
    int l = idx / EMAX, e = idx - l * EMAX;
    int E = row_ptr[MM];
    if (e < E) {
        unsigned pk = edge_csr[e];
        size_t src = (size_t)l * (MM * NN) + (size_t)(pk >> 16) * NN + (pk & 0xffffu);
        wde_p[idx]  = w_de[src];
        mwde_p[idx] = mw_de[src];
    } else {
        wde_p[idx]  = 0.0f;    // padded slots: defined zeros
        mwde_p[idx] = 0.0f;
    }
}

// ---- main BP kernel: ONE workgroup per batch, everything in LDS ----
// No grid barrier, no threadfence, no HBM partial round trips.
// amdgpu_waves_per_eu(4,4): a 1024-thread workgroup forces 4 waves/EU anyway;
// pinning min AND max raises the VGPR budget to 128. (__launch_bounds__(1024,4)
// only sets the min -> compiler still targeted 8 waves/EU -> 64-VGPR cap ->
// scratch spills -> rounds 1-2 at ~1300 us with VALUBusy 0.25%.)
__global__ __launch_bounds__(NT)
__attribute__((amdgpu_waves_per_eu(4, 4)))
void nbp_main(const int* __restrict__ synd, const int* __restrict__ errs,
              const float* __restrict__ llrs,
              const float* __restrict__ w_llr, const float* __restrict__ mw_llr,
              const float* __restrict__ rhos, const float* __restrict__ resw,
              const int* __restrict__ row_ptr, const float* __restrict__ row_offf,
              const unsigned* __restrict__ edge_csr,
              const float* __restrict__ wde_p, const float* __restrict__ mwde_p,
              float* __restrict__ out) {
    __shared__ float colsum_s[NN];        // full column sums for current layer
    __shared__ float bel_s[NN];           // belief edge contributions (atomic)
    __shared__ float ncs_s[NN];           // next-layer colsum edge contributions
    __shared__ float partial_s[PMAX * MM];// [q][row] segmented row products
    __shared__ float rowprod_s[MM];
    __shared__ float rp_coef[MM];         // row_offf * (-1)^syndrome
    __shared__ int   rowptr_s[MM + 1];
    __shared__ float rho_n[LL];
    __shared__ float red[16];
    // ~47.2 KB total

    const int b = blockIdx.x;             // one block per batch
    const int tid = threadIdx.x;
    const int lane = tid & 63, wave = tid >> 6;
    const int s0 = EPT * tid;             // this thread's first edge slot

    // ---- prologue ----
    if (tid == 0) {
        float mx = -1e30f;
        for (int l = 0; l < LL; ++l) mx = fmaxf(mx, rhos[l]);
        float s = 0.0f;
        for (int l = 0; l < LL; ++l) { float e = __expf(rhos[l] - mx); rho_n[l] = e; s += e; }
        for (int l = 0; l < LL; ++l) rho_n[l] /= s;
    }
    if (tid < MM) {
        rowptr_s[tid] = row_ptr[tid];
        rp_coef[tid] = row_offf[tid] * (1.0f - 2.0f * (float)synd[b * MM + tid]);
    }
    if (tid == MM) rowptr_s[MM] = row_ptr[MM];

    // each thread permanently owns output columns j0, j1
    const int j0 = tid, j1 = tid + NT;
    const float llr0 = llrs[j0], llr1 = llrs[j1];
    const float ef0 = 1.0f - (float)errs[b * NN + j0];
    const float ef1 = 1.0f - (float)errs[b * NN + j1];
    colsum_s[j0] = llr0 * w_llr[j0];      // layer-0 colsum: msgs are zero
    colsum_s[j1] = llr1 * w_llr[j1];
    bel_s[j0] = 0.0f; bel_s[j1] = 0.0f;
    ncs_s[j0] = 0.0f; ncs_s[j1] = 0.0f;

    int cnt = row_ptr[MM];
    if (cnt > EMAX) cnt = EMAX;

    // per-thread contiguous edge state (CSR order): 48 persistent VGPRs
    // (d is recomputed in phase D from colsum_s + old msg -> no d_r[] array)
    unsigned idx[EPT];
    float msg[EPT];
    #pragma unroll
    for (int k = 0; k < EPT; ++k) {
        int e = s0 + k;
        idx[k] = edge_csr[e < cnt ? e : (cnt - 1)];   // padded: clone last real edge
        msg[k] = 0.0f;
    }
    __syncthreads();

    float loss = 0.0f;

    for (int l = 0; l < LL; ++l) {
        const float rw = resw[l];
        const bool last = (l + 1 == LL);

        // ---- B: per-edge tanh (d) + segmented per-row partial products ----
        if (s0 < cnt) {
            int crow = idx[0] >> 16;
            int q = tid - rowptr_s[crow] / EPT;   // slot within row's thread span
            float p = 1.0f;
            #pragma unroll
            for (int k = 0; k < EPT; ++k) {
                int rk = idx[k] >> 16;
                if (rk != crow) {                 // row starts inside this thread -> q=0
                    partial_s[q * MM + crow] = p;
                    crow = rk; q = 0; p = 1.0f;
                }
                if (s0 + k < cnt) {
                    int j = idx[k] & 0xffffu;
                    float en = colsum_s[j] - msg[k];
                    float t = __expf(en);                     // tanh(en/2)=1-2/(e^en+1)
                    float d = 1.0f - 2.0f * __builtin_amdgcn_rcpf(t + 1.0f);
                    if (d == 0.0f) d = 1.0f;                  // ref: where(d==0,1,d)
                    d = fminf(fmaxf(d, -1.0f + EPSV), 1.0f - EPSV);
                    p *= d;                                   // padded slots contribute 1.0
                }
            }
            partial_s[q * MM + crow] = p;
        }
        __syncthreads();

        // ---- C: combine <=7 partials per row (lane-consecutive, conflict-free) ----
        if (tid < MM) {
            int lo = rowptr_s[tid], hi = rowptr_s[tid + 1];
            float p = 1.0f;
            if (hi > lo) {
                int f = lo / EPT;
                int span = (hi - 1) / EPT - f + 1;
                for (int q = 0; q < span; ++q) p *= partial_s[q * MM + tid];
            }
            rowprod_s[tid] = p * rp_coef[tid];    // sign + off-support factor folded in
        }
        __syncthreads();

        // ---- D: recompute d, atanh + msg update + dual LDS scatter ----
        // Weights streamed in 6 float4 chunks, 1-ahead double buffer; chunk
        // boundaries pinned with sched_barrier so the unroller can't hoist all
        // 12 loads and blow the register budget.
        {
            const float4* mp = (const float4*)(mwde_p + (size_t)l * EMAX + s0);
            const float4* wp = (const float4*)(wde_p + (size_t)(l + 1) * EMAX + s0);
            float4 mq0 = mp[0];
            float4 wq0 = last ? make_float4(0.f, 0.f, 0.f, 0.f) : wp[0];
            #pragma unroll
            for (int q = 0; q < EPT / 4; ++q) {
                float4 mq1 = make_float4(0.f, 0.f, 0.f, 0.f);
                float4 wq1 = make_float4(0.f, 0.f, 0.f, 0.f);
                if (q + 1 < EPT / 4) {
                    mq1 = mp[q + 1];
                    if (!last) wq1 = wp[q + 1];
                }
                const float mvv[4] = {mq0.x, mq0.y, mq0.z, mq0.w};
                const float wnv[4] = {wq0.x, wq0.y, wq0.z, wq0.w};
                #pragma unroll
                for (int kk = 0; kk < 4; ++kk) {
                    const int k = 4 * q + kk;
                    int il = idx[k] >> 16;
                    int j  = idx[k] & 0xffffu;
                    // recompute d (bit-identical to phase B: colsum_s unchanged
                    // until E, msg[k] read before overwrite)
                    float en = colsum_s[j] - msg[k];
                    float t = __expf(en);
                    float d = 1.0f - 2.0f * __builtin_amdgcn_rcpf(t + 1.0f);
                    if (d == 0.0f) d = 1.0f;
                    d = fminf(fmaxf(d, -1.0f + EPSV), 1.0f - EPSV);
                    float rq = rowprod_s[il] * __builtin_amdgcn_rcpf(d);
                    // sgn*2*atanh(x) = 2*atanh(sgn*x); sgn folded into rp_coef
                    float v = __logf(1.0f + rq) - __logf(1.0f - rq) + rw * msg[k];
                    msg[k] = v;
                    if (s0 + k < cnt) {
                        atomicAdd(&bel_s[j], v * mvv[kk]);
                        if (!last) atomicAdd(&ncs_s[j], v * wnv[kk]);
                    }
                }
                mq0 = mq1; wq0 = wq1;
                __builtin_amdgcn_sched_barrier(0);
            }
        }
        __syncthreads();

        // ---- E: loss on own 2 columns + next-layer colsum + re-zero partials ----
        {
            float bel0 = llr0 * mw_llr[l * NN + j0] + bel_s[j0];
            float bel1 = llr1 * mw_llr[l * NN + j1] + bel_s[j1];
            bel_s[j0] = 0.0f; bel_s[j1] = 0.0f;
            float sp0 = fmaxf(bel0, 0.0f) + log1pf(__expf(-fabsf(bel0)));  // softplus
            float sp1 = fmaxf(bel1, 0.0f) + log1pf(__expf(-fabsf(bel1)));
            loss += rho_n[l] * ((sp0 - ef0 * bel0) + (sp1 - ef1 * bel1));
            if (!last) {
                colsum_s[j0] = llr0 * w_llr[(l + 1) * NN + j0] + ncs_s[j0];
                colsum_s[j1] = llr1 * w_llr[(l + 1) * NN + j1] + ncs_s[j1];
                ncs_s[j0] = 0.0f; ncs_s[j1] = 0.0f;
            }
        }
        __syncthreads();
    }

    // ---- block reduction of loss, then one global atomic ----
    #pragma unroll
    for (int off = 32; off > 0; off >>= 1) loss += __shfl_down(loss, off);
    if (lane == 0) red[wave] = loss;
    __syncthreads();
    if (wave == 0) {
        float v = (lane < 16) ? red[lane] : 0.0f;
        #pragma unroll
        for (int off = 8; off > 0; off >>= 1) v += __shfl_down(v, off);
        if (lane == 0) atomicAdd(out, v * 0.25f);
    }
}

extern "C" void kernel_launch(void* const* d_in, const int* in_sizes, int n_in,
                              void* d_out, int out_size, void* d_ws, size_t ws_size,
                              hipStream_t stream) {
    const int*   synd  = (const int*)  d_in[0];
    const int*   errs  = (const int*)  d_in[1];
    const float* H     = (const float*)d_in[2];
    const float* llrs  = (const float*)d_in[3];
    const float* w_de  = (const float*)d_in[4];
    const float* w_llr = (const float*)d_in[5];
    const float* mw_de = (const float*)d_in[6];
    const float* mw_llr= (const float*)d_in[7];
    const float* rhos  = (const float*)d_in[8];
    const float* resw  = (const float*)d_in[9];

    char* ws = (char*)d_ws;
    int*      row_deg  = (int*)     (ws + WS_ROW_DEG);
    int*      row_pad  = (int*)     (ws + WS_ROW_PAD);
    float*    row_offf = (float*)   (ws + WS_ROW_OFFF);
    int*      row_ptr  = (int*)     (ws + WS_ROW_PTR);
    unsigned* edge_csr = (unsigned*)(ws + WS_EDGE_CSR);
    float*    wde_p    = (float*)   (ws + WS_WDE_P);
    float*    mwde_p   = (float*)   (ws + WS_MWDE_P);
    float*    out      = (float*)d_out;

    hipMemsetAsync(d_out, 0, sizeof(float), stream);

    build_rows<<<MM, 64, 0, stream>>>(H, row_deg, row_pad, row_offf);
    scan_rows<<<1, 512, 0, stream>>>(row_deg, row_ptr);
    fill_csr<<<MM, 64, 0, stream>>>(row_deg, row_pad, row_ptr, edge_csr);
    gather_weights<<<(LL * EMAX) / 256, 256, 0, stream>>>(w_de, mw_de, edge_csr,
                                                          row_ptr, wde_p, mwde_p);
    nbp_main<<<BB, NT, 0, stream>>>(synd, errs, llrs, w_llr, mw_llr, rhos, resw,
                                    row_ptr, row_offf, edge_csr, wde_p, mwde_p, out);
}

// Round 5
// 424.673 us; speedup vs baseline: 3.5534x; 3.4023x over previous
//
#include <hip/hip_runtime.h>

// M=512, N=2048, B=4, L=20, H density 0.02 (row weight ~41, col weight ~10).
#define MM 512
#define NN 2048
#define BB 4
#define LL 20
#define MAXDEG 128      // per-row cap (~13 sigma)
#define EMAX  24576     // edge cap; actual E ~20973
#define NT    1024
#define RR    8         // blocks per batch (row-partitioned)
#define ROWSB 64        // MM / RR rows per block
#define SLOTS 4096      // padded edge slots per block (~2621 expected, +29 sigma)
#define COLSB 256       // NN / RR loss columns per block
#define EPSV  1e-6f

// ---------------- workspace layout (bytes) ----------------
#define WS_ROW_DEG   0          // int[512]
#define WS_ROW_PAD   2048       // int[512*128]
#define WS_ROW_OFFF  264192     // float[512]
#define WS_ROW_PTR   266240     // int[513] (pad to 268416)
#define WS_EDGE_CSR  268416     // uint[EMAX] (row<<16|col), CSR order
#define WS_WDE_P     366720     // float[L*RR*SLOTS]  per-block padded, 16B-aligned segs
#define WS_MWDE_P    2988160    // float[L*RR*SLOTS]
#define WS_COLPART   5609600    // float[2*B*RR*NN]  (layer-parity double buffer)
#define WS_BELPART   6133888    // float[2*B*RR*NN]
#define WS_BAR       6658176    // int[B*64] barrier counters (memset 0 each launch)
// total ~6.66 MB

// ---- k1: one wave per row, ballot-compact H row into padded list ----
// all 32 chunk loads issued before the serial ballot chain (latency hidden once)
__global__ __launch_bounds__(64)
void build_rows(const float* __restrict__ H, int* __restrict__ row_deg,
                int* __restrict__ row_pad, float* __restrict__ row_offf) {
    int i = blockIdx.x, lane = threadIdx.x;
    const float* hrow = H + (size_t)i * NN;
    float v[32];
    #pragma unroll
    for (int c = 0; c < 32; ++c) v[c] = hrow[c * 64 + lane];
    int base = 0;
    #pragma unroll
    for (int c = 0; c < 32; ++c) {
        bool pred = v[c] != 0.0f;
        unsigned long long mask = __ballot(pred);
        int before = __popcll(mask & ((1ull << lane) - 1ull));
        if (pred) {
            int k = base + before;
            if (k < MAXDEG) row_pad[i * MAXDEG + k] = c * 64 + lane;
        }
        base += __popcll(mask);
    }
    if (lane == 0) {
        row_deg[i] = base < MAXDEG ? base : MAXDEG;
        // off-support entries contribute clip(1.0)=1-eps each to the row product
        row_offf[i] = powf(1.0f - EPSV, (float)(NN - base));
    }
}

// ---- k2: exclusive prefix sum of row degrees (single block) ----
__global__ __launch_bounds__(512)
void scan_rows(const int* __restrict__ row_deg, int* __restrict__ row_ptr) {
    __shared__ int tmp[512];
    int t = threadIdx.x;
    tmp[t] = row_deg[t];
    __syncthreads();
    for (int off = 1; off < 512; off <<= 1) {
        int v = (t >= off) ? tmp[t - off] : 0;
        __syncthreads();
        tmp[t] += v;
        __syncthreads();
    }
    if (t == 0) row_ptr[0] = 0;
    row_ptr[t + 1] = tmp[t];
}

// ---- k3: fill CSR edge list ----
__global__ __launch_bounds__(64)
void fill_csr(const int* __restrict__ row_deg, const int* __restrict__ row_pad,
              const int* __restrict__ row_ptr, unsigned* __restrict__ edge_csr) {
    int i = blockIdx.x, lane = threadIdx.x;
    int deg = row_deg[i], base = row_ptr[i];
    for (int k = lane; k < deg; k += 64)
        edge_csr[base + k] = ((unsigned)i << 16) | (unsigned)row_pad[i * MAXDEG + k];
}

// ---- k4: gather dense weights into per-block padded segments ----
// layout: [l][r][s], segment bases 16B-aligned -> float4 loads in nbp_main
__global__ __launch_bounds__(256)
void gather_weights(const float* __restrict__ w_de, const float* __restrict__ mw_de,
                    const unsigned* __restrict__ edge_csr, const int* __restrict__ row_ptr,
                    float* __restrict__ wde_p, float* __restrict__ mwde_p) {
    int idx = blockIdx.x * 256 + threadIdx.x;       // 0 .. L*RR*SLOTS-1
    int l = idx / (RR * SLOTS);
    int rem = idx - l * (RR * SLOTS);
    int r = rem / SLOTS, s = rem - r * SLOTS;
    int e = row_ptr[r * ROWSB] + s;
    if (e < row_ptr[(r + 1) * ROWSB]) {
        unsigned pk = edge_csr[e];
        size_t src = (size_t)l * MM * NN + (size_t)(pk >> 16) * NN + (pk & 0xffffu);
        wde_p[idx]  = w_de[src];
        mwde_p[idx] = mw_de[src];
    } else {
        wde_p[idx]  = 0.0f;    // padded slots: defined zeros
        mwde_p[idx] = 0.0f;
    }
}

// ---- device-scope barrier across the RR blocks of one batch ----
// NO __threadfence: on gfx95x an agent fence emits buffer_wbl2/buffer_inv (full
// local-L2 writeback+invalidate) each layer, evicting the cached weights too.
// Instead, the exchanged partials are accessed exclusively with agent-scope
// RELAXED atomic load/store (coherent SC policy bits, write-through past the
// non-coherent per-XCD L2, valid cross-XCD at the MALL), so no cache flush is
// needed. Release ordering: __syncthreads() drains vmcnt(0) per wave before
// s_barrier; tid0's explicit waitcnt covers its own stores. Acquire: control
// dependency + trailing __syncthreads. Fresh counter per layer (no ABA).
// FAILSAFE: spin is bounded (~100 ms). If the coherence reasoning is wrong the
// kernel produces a detectably wrong answer instead of hanging the container.
__device__ __forceinline__ void grid_barrier(int* ctr) {
    __syncthreads();
    if (threadIdx.x == 0) {
        asm volatile("s_waitcnt vmcnt(0)" ::: "memory");
        __hip_atomic_fetch_add(ctr, 1, __ATOMIC_RELAXED, __HIP_MEMORY_SCOPE_AGENT);
        int it = 0;
        while (__hip_atomic_load(ctr, __ATOMIC_RELAXED, __HIP_MEMORY_SCOPE_AGENT) < RR) {
            __builtin_amdgcn_s_sleep(1);
            if (++it > (1 << 22)) break;     // bounded: hang -> wrong answer, not死机
        }
        asm volatile("" ::: "memory");
    }
    __syncthreads();
}

// ---- main BP kernel: 32 blocks = 4 batches x 8 row-partitions ----
__global__ __launch_bounds__(NT, 4)
void nbp_main(const int* __restrict__ synd, const int* __restrict__ errs,
              const float* __restrict__ llrs,
              const float* __restrict__ w_llr, const float* __restrict__ mw_llr,
              const float* __restrict__ rhos, const float* __restrict__ resw,
              const int* __restrict__ row_ptr, const float* __restrict__ row_offf,
              const unsigned* __restrict__ edge_csr,
              const float* __restrict__ wde_p, const float* __restrict__ mwde_p,
              float* __restrict__ colpart, float* __restrict__ belpart,
              int* __restrict__ bar, float* __restrict__ out) {
    __shared__ float d_sb[SLOTS];         // 16 KB, block-local d, float4 stores
    __shared__ float colsum_s[NN];        // total colsum for current layer
    __shared__ float bel_s[NN];           // belief partial (edge contributions)
    __shared__ float ncs_s[NN];           // next-layer colsum partial
    __shared__ float llrs_s[NN];
    __shared__ float rowprod_s[ROWSB];
    __shared__ float rp_coef[ROWSB];      // row_offf * (-1)^syndrome
    __shared__ int   rowptr_s[ROWSB + 1];
    __shared__ float rho_n[LL];
    __shared__ float red[16];

    const int blk = blockIdx.x;
    const int b = blk & 3, r = blk >> 2;
    const int i0 = r * ROWSB;
    const int tid = threadIdx.x;
    const int lane = tid & 63, wave = tid >> 6;

    int* bar_b = bar + b * 64;

    // ---- prologue ----
    if (tid == 0) {
        float mx = -1e30f;
        for (int l = 0; l < LL; ++l) mx = fmaxf(mx, rhos[l]);
        float s = 0.0f;
        for (int l = 0; l < LL; ++l) { float e = __expf(rhos[l] - mx); rho_n[l] = e; s += e; }
        for (int l = 0; l < LL; ++l) rho_n[l] /= s;
    }
    if (tid < ROWSB) {
        int i = i0 + tid;
        rowptr_s[tid] = row_ptr[i];
        rp_coef[tid] = row_offf[i] * (1.0f - 2.0f * (float)synd[b * MM + i]);
    }
    if (tid == ROWSB) rowptr_s[ROWSB] = row_ptr[i0 + ROWSB];
    for (int j = tid; j < NN; j += NT) {
        float lj = llrs[j];
        llrs_s[j] = lj;
        colsum_s[j] = lj * w_llr[j];       // layer-0 colsum: msgs are zero
    }

    const int e_lo = row_ptr[i0], e_hi = row_ptr[i0 + ROWSB];
    const int cnt = e_hi - e_lo;
    const int s0 = 4 * tid;                // this thread's first local slot

    // per-thread contiguous edge state
    unsigned idx[4];
    float msg[4], d_r[4];
    #pragma unroll
    for (int k = 0; k < 4; ++k) {
        int e = e_lo + s0 + k;
        idx[k] = edge_csr[(s0 + k) < cnt ? e : e_lo] - ((unsigned)i0 << 16);
        msg[k] = 0.0f;
    }
    __syncthreads();

    float loss = 0.0f;

    for (int l = 0; l < LL; ++l) {
        const float rw = resw[l];
        const int par = l & 1;
        float* colpart_b = colpart + ((size_t)par * BB + b) * RR * NN;
        float* belpart_b = belpart + ((size_t)par * BB + b) * RR * NN;

        // ---- B: prefetch weights (aligned float4) + per-edge tanh ----
        const float4 mq = *(const float4*)(mwde_p + ((size_t)(l * RR + r) * SLOTS) + s0);
        float4 wq = make_float4(0.f, 0.f, 0.f, 0.f);
        if (l + 1 < LL)
            wq = *(const float4*)(wde_p + ((size_t)((l + 1) * RR + r) * SLOTS) + s0);
        const float mv[4] = {mq.x, mq.y, mq.z, mq.w};
        const float wn[4] = {wq.x, wq.y, wq.z, wq.w};

        #pragma unroll
        for (int k = 0; k < 4; ++k) {
            int j = idx[k] & 0xffffu;
            float en = colsum_s[j] - msg[k];
            float t = __expf(en);                             // tanh(en/2)=1-2/(e^en+1)
            float d = 1.0f - 2.0f * __builtin_amdgcn_rcpf(t + 1.0f);
            if (d == 0.0f) d = 1.0f;                          // ref: where(d==0,1,d)
            d = fminf(fmaxf(d, -1.0f + EPSV), 1.0f - EPSV);
            d_r[k] = d;
        }
        *(float4*)&d_sb[s0] = make_float4(d_r[0], d_r[1], d_r[2], d_r[3]);
        __syncthreads();

        // ---- C: row products, 4 threads/row | zero bel/ncs partials ----
        if (tid < 4 * ROWSB) {
            int i = tid >> 2, q = tid & 3;
            int s = rowptr_s[i] - e_lo;
            int deg = rowptr_s[i + 1] - rowptr_s[i];
            float p = 1.0f;
            for (int c = q; c < deg; c += 4) p *= d_sb[s + c];
            p *= __shfl_xor(p, 1);
            p *= __shfl_xor(p, 2);
            if (q == 0) rowprod_s[i] = p * rp_coef[i];        // sign folded in
        } else {
            for (int j = tid - 4 * ROWSB; j < NN; j += NT - 4 * ROWSB) {
                bel_s[j] = 0.0f;
                ncs_s[j] = 0.0f;
            }
        }
        __syncthreads();

        // ---- D: atanh + msg update + dual scatter (bel + next colsum) ----
        #pragma unroll
        for (int k = 0; k < 4; ++k) {
            int il = idx[k] >> 16;
            int j  = idx[k] & 0xffffu;
            float rq = rowprod_s[il] * __builtin_amdgcn_rcpf(d_r[k]);
            // sgn*2*atanh(x) = 2*atanh(sgn*x); sgn folded into rp_coef
            float v = __logf(1.0f + rq) - __logf(1.0f - rq) + rw * msg[k];
            msg[k] = v;
            if (s0 + k < cnt) {
                atomicAdd(&bel_s[j], v * mv[k]);
                if (l + 1 < LL) atomicAdd(&ncs_s[j], v * wn[k]);
            }
        }
        __syncthreads();
        // partial exchange: coherent (agent-scope) stores, no cache flush needed
        for (int j = tid; j < NN; j += NT) {
            __hip_atomic_store(&belpart_b[r * NN + j], bel_s[j],
                               __ATOMIC_RELAXED, __HIP_MEMORY_SCOPE_AGENT);
            __hip_atomic_store(&colpart_b[r * NN + j], ncs_s[j],
                               __ATOMIC_RELAXED, __HIP_MEMORY_SCOPE_AGENT);
        }
        grid_barrier(&bar_b[l]);

        // ---- E: loss on column slice + total colsum for next layer ----
        if (tid < COLSB) {
            int j = r * COLSB + tid;
            float bel = llrs_s[j] * mw_llr[l * NN + j];
            float* bp = belpart_b + j;
            #pragma unroll
            for (int r2 = 0; r2 < RR; ++r2)
                bel += __hip_atomic_load(&bp[r2 * NN],
                                         __ATOMIC_RELAXED, __HIP_MEMORY_SCOPE_AGENT);
            float sp = fmaxf(bel, 0.0f) + log1pf(__expf(-fabsf(bel)));  // softplus
            loss += rho_n[l] * (sp - (1.0f - (float)errs[b * NN + j]) * bel);
        }
        if (l + 1 < LL) {
            const float* wl_next = w_llr + (l + 1) * NN;
            for (int j = tid; j < NN; j += NT) {
                float s = llrs_s[j] * wl_next[j];
                float* cp = colpart_b + j;
                #pragma unroll
                for (int r2 = 0; r2 < RR; ++r2)
                    s += __hip_atomic_load(&cp[r2 * NN],
                                           __ATOMIC_RELAXED, __HIP_MEMORY_SCOPE_AGENT);
                colsum_s[j] = s;
            }
        }
        __syncthreads();
        // safe w.r.t. next layer: partial buffers are parity double-buffered,
        // so D(l+1) writes the other buffer while any straggler still reads this one.
    }

    // ---- block reduction of loss, then one global atomic ----
    #pragma unroll
    for (int off = 32; off > 0; off >>= 1) loss += __shfl_down(loss, off);
    if (lane == 0) red[wave] = loss;
    __syncthreads();
    if (wave == 0) {
        float v = (lane < 16) ? red[lane] : 0.0f;
        #pragma unroll
        for (int off = 8; off > 0; off >>= 1) v += __shfl_down(v, off);
        if (lane == 0) atomicAdd(out, v * 0.25f);
    }
}

extern "C" void kernel_launch(void* const* d_in, const int* in_sizes, int n_in,
                              void* d_out, int out_size, void* d_ws, size_t ws_size,
                              hipStream_t stream) {
    const int*   synd  = (const int*)  d_in[0];
    const int*   errs  = (const int*)  d_in[1];
    const float* H     = (const float*)d_in[2];
    const float* llrs  = (const float*)d_in[3];
    const float* w_de  = (const float*)d_in[4];
    const float* w_llr = (const float*)d_in[5];
    const float* mw_de = (const float*)d_in[6];
    const float* mw_llr= (const float*)d_in[7];
    const float* rhos  = (const float*)d_in[8];
    const float* resw  = (const float*)d_in[9];

    char* ws = (char*)d_ws;
    int*      row_deg  = (int*)     (ws + WS_ROW_DEG);
    int*      row_pad  = (int*)     (ws + WS_ROW_PAD);
    float*    row_offf = (float*)   (ws + WS_ROW_OFFF);
    int*      row_ptr  = (int*)     (ws + WS_ROW_PTR);
    unsigned* edge_csr = (unsigned*)(ws + WS_EDGE_CSR);
    float*    wde_p    = (float*)   (ws + WS_WDE_P);
    float*    mwde_p   = (float*)   (ws + WS_MWDE_P);
    float*    colpart  = (float*)   (ws + WS_COLPART);
    float*    belpart  = (float*)   (ws + WS_BELPART);
    int*      bar      = (int*)     (ws + WS_BAR);
    float*    out      = (float*)d_out;

    hipMemsetAsync(bar, 0, BB * 64 * sizeof(int), stream);
    hipMemsetAsync(d_out, 0, sizeof(float), stream);

    build_rows<<<MM, 64, 0, stream>>>(H, row_deg, row_pad, row_offf);
    scan_rows<<<1, 512, 0, stream>>>(row_deg, row_ptr);
    fill_csr<<<MM, 64, 0, stream>>>(row_deg, row_pad, row_ptr, edge_csr);
    gather_weights<<<(LL * RR * SLOTS) / 256, 256, 0, stream>>>(w_de, mw_de, edge_csr,
                                                                row_ptr, wde_p, mwde_p);
    nbp_main<<<BB * RR, NT, 0, stream>>>(synd, errs, llrs, w_llr, mw_llr, rhos, resw,
                                         row_ptr, row_offf, edge_csr, wde_p, mwde_p,
                                         colpart, belpart, bar, out);
}